// Round 1
// baseline (371.774 us; speedup 1.0000x reference)
//
#include <hip/hip_runtime.h>
#include <hip/hip_bf16.h>

typedef _Float16 half8 __attribute__((ext_vector_type(8)));
typedef _Float16 half4v __attribute__((ext_vector_type(4)));
typedef float floatx4 __attribute__((ext_vector_type(4)));
typedef float floatx16 __attribute__((ext_vector_type(16)));

// ---------------------------------------------------------------------------
// R17: 128x128 wave tile (4m x 4n frags, 256 acc regs), BM=128, 2-wave blocks.
// Rationale: W L2-traffic scales 1/m_per_wave, A LDS-traffic 1/n_per_wave;
// at 64x64 both terms (~4.3 GB L2, ~5.1 GB LDS) rivaled the 104 us MFMA floor
// and barely overlapped (44% MfmaUtil). 128x128 halves both; per k-step a
// wave issues 16 MFMA (512 SIMD-cy) vs 4 ds_read_b128 + 4 global 16B loads
// -> ~32 B/cy/CU on LDS and L2, far under ceilings. Depth-1 prefetch of W+A
// covers L2 latency inside the 512-cy window, so 1 wave/SIMD suffices.
//
// Act layout: chunk-major with 128-row chunks:
//   off(row, col) = (col>>3)*1024 + row*8 + (col&7)   [halfs]
// A-frag (kstep ks, m-frag mi): base = lhi*1024 + (mi*32+l31)*8, +ks*2048
// (<= 15*4096 B immediate — fits 16-bit ds offset; L5 ks>=16 reads x-buffer).
// LDS: act 128x256 fp16 (64 KiB, in-place) + x 128x48 (12 KiB) = 76 KiB
// -> 2 blocks/CU (152 KiB of 160). 4 waves/CU = 1/SIMD; launch_bounds(128,1)
// gives the full 512-reg unified VGPR/AGPR budget (256 acc + ~130 VGPR).
// ---------------------------------------------------------------------------
__device__ __forceinline__ int cmaj(int row, int col) {
    return ((col >> 3) << 10) + (row << 3) + (col & 7);
}

// ---------------------------------------------------------------------------
// Weight pre-pack (unchanged, proven R5-R16): fp32 (K,N) row-major -> fp16
// fragment order; lane L holds W[kt*16 + 8*(L>>5) + j][nt*32 + (L&31)].
// Fed to the MFMA *A* operand so D = C^T. K zero-padded: L1 39->64 (KT=4),
// L5 295->320 (KT=20), others 256 (KT=16). L9 N 4->32. Tile starts (1KB):
// {0,32,160,288,416,576,704,832,960}, total 976 tiles = 999424 B in d_ws.
// (R17 consumes only kt 0..2 of L1 and kt 0..18 of L5 — the rest is zeros.)
// ---------------------------------------------------------------------------
__global__ void pack_w32(const float* __restrict__ w1, const float* __restrict__ w2,
                         const float* __restrict__ w3, const float* __restrict__ w4,
                         const float* __restrict__ w5, const float* __restrict__ w6,
                         const float* __restrict__ w7, const float* __restrict__ w8,
                         const float* __restrict__ w9, _Float16* __restrict__ dst) {
    const int tileStart[10] = {0, 32, 160, 288, 416, 576, 704, 832, 960, 976};
    const int Ks[9] = {39, 256, 256, 256, 295, 256, 256, 256, 256};
    const int Ns[9] = {256, 256, 256, 256, 256, 256, 256, 256, 4};
    const int Tn[9] = {8, 8, 8, 8, 8, 8, 8, 8, 1};
    const float* ws[9] = {w1, w2, w3, w4, w5, w6, w7, w8, w9};

    int g = blockIdx.x * blockDim.x + threadIdx.x;
    int tile = g >> 6, lane = g & 63;
    if (tile >= 976) return;
    int layer = 0;
    while (tile >= tileStart[layer + 1]) layer++;
    int t = tile - tileStart[layer];
    int tn = Tn[layer];
    int kt = t / tn, nt = t - kt * tn;
    int k0 = kt * 16 + (lane >> 5) * 8;
    int n = nt * 32 + (lane & 31);
    const float* w = ws[layer];
    int K = Ks[layer], N = Ns[layer];
    _Float16 v[8];
#pragma unroll
    for (int j = 0; j < 8; j++) {
        int k = k0 + j;
        v[j] = (k < K && n < N) ? (_Float16)w[k * N + n] : (_Float16)0.f;
    }
    *(half8*)(dst + (size_t)tile * 512 + lane * 8) = *(half8*)v;
}

// A-fragment load: base encodes (lhi, m-frag row); offset linear in ks.
// AMODE 0: act. 1: ks>=KS0 from x (layer-5 skip). 2: entirely x (layer 1).
template <int AMODE, int KS0>
__device__ __forceinline__ half8 ldA(const _Float16* aB, const _Float16* xB, int ks) {
    if (AMODE == 2) return *(const half8*)(xB + ks * 2048);
    if (AMODE == 1 && ks >= KS0) return *(const half8*)(xB + (ks - KS0) * 2048);
    return *(const half8*)(aB + ks * 2048);
}

// ---------------------------------------------------------------------------
// One fused layer: C(128x256) = relu(A(128xK) @ W + b), in-place LDS->LDS.
// Wave tile 128x128: per kstep 4 A-frags (ds_read_b128) + 4 W-frags
// (global 16B, L2-resident) + 16 MFMA; depth-1 prefetch of both streams.
// Bias folded into acc init; b64 epilogue (same per-frag D mapping as R16:
// col = nbase + lhi*4 + g*8 + r, row = mi*32 + l31).
// ---------------------------------------------------------------------------
template <int KT, int AMODE, int KS0>
__device__ __forceinline__ void layerT(const _Float16* abuf,
                                       const _Float16* __restrict__ xbuf,
                                       const half8* __restrict__ wq,
                                       const float* __restrict__ bias,
                                       _Float16* obuf,
                                       int lane, int wave) {
    const int l31 = lane & 31, lhi = lane >> 5;
    const _Float16* aB[4];
    const _Float16* xB[4];
#pragma unroll
    for (int mi = 0; mi < 4; mi++) {
        aB[mi] = abuf + lhi * 1024 + (mi * 32 + l31) * 8;
        xB[mi] = xbuf + lhi * 1024 + (mi * 32 + l31) * 8;
    }
    // W frag (kstep ks, n-tile wave*4+ni): wl[ks*512 + ni*64]
    const half8* wl = wq + (wave * 4) * 64 + lane;

    // Bias -> acc init: acc element g*4+r is channel wave*128 + ni*32 + lhi*4 + g*8 + r.
    floatx16 acc[4][4];
#pragma unroll
    for (int ni = 0; ni < 4; ni++) {
        floatx16 t;
#pragma unroll
        for (int g = 0; g < 4; g++) {
            floatx4 b = *(const floatx4*)(bias + wave * 128 + ni * 32 + g * 8 + lhi * 4);
#pragma unroll
            for (int r = 0; r < 4; r++) t[g * 4 + r] = b[r];
        }
#pragma unroll
        for (int mi = 0; mi < 4; mi++) acc[mi][ni] = t;
    }

    half8 wc[4], ac[4];
#pragma unroll
    for (int ni = 0; ni < 4; ni++) wc[ni] = wl[ni * 64];
#pragma unroll
    for (int mi = 0; mi < 4; mi++) ac[mi] = ldA<AMODE, KS0>(aB[mi], xB[mi], 0);

#pragma unroll 1
    for (int ks = 0; ks < KT - 1; ks++) {
        half8 wn[4], an[4];
#pragma unroll
        for (int ni = 0; ni < 4; ni++) wn[ni] = wl[(ks + 1) * 512 + ni * 64];
#pragma unroll
        for (int mi = 0; mi < 4; mi++) an[mi] = ldA<AMODE, KS0>(aB[mi], xB[mi], ks + 1);
#pragma unroll
        for (int mi = 0; mi < 4; mi++)
#pragma unroll
            for (int ni = 0; ni < 4; ni++)
                acc[mi][ni] = __builtin_amdgcn_mfma_f32_32x32x16_f16(wc[ni], ac[mi],
                                                                     acc[mi][ni], 0, 0, 0);
#pragma unroll
        for (int ni = 0; ni < 4; ni++) wc[ni] = wn[ni];
#pragma unroll
        for (int mi = 0; mi < 4; mi++) ac[mi] = an[mi];
    }
#pragma unroll
    for (int mi = 0; mi < 4; mi++)
#pragma unroll
        for (int ni = 0; ni < 4; ni++)
            acc[mi][ni] = __builtin_amdgcn_mfma_f32_32x32x16_f16(wc[ni], ac[mi],
                                                                 acc[mi][ni], 0, 0, 0);

    // In-place safety barrier: all waves' act-reads complete before any write.
    if (AMODE != 2) __syncthreads();
    // Epilogue: relu + fp16 cvt + b64 writes (bias already in acc).
    // col = wave*128 + ni*32 + g*8 + lhi*4 + r -> chunk = wave*16 + ni*4 + g,
    // inner = lhi*4 + r.
#pragma unroll
    for (int mi = 0; mi < 4; mi++) {
        _Float16* ob = obuf + (mi * 32 + l31) * 8 + lhi * 4;
#pragma unroll
        for (int ni = 0; ni < 4; ni++) {
#pragma unroll
            for (int g = 0; g < 4; g++) {
                half4v h;
#pragma unroll
                for (int r = 0; r < 4; r++) {
                    float v = acc[mi][ni][g * 4 + r];
                    v = v > 0.f ? v : 0.f;
                    h[r] = (_Float16)v;
                }
                *(half4v*)(ob + (wave * 16 + ni * 4 + g) * 1024) = h;
            }
        }
    }
}

// Layer 9 (swapped): 256 -> 4 (N padded to 32). Each wave takes 64 rows
// (2 m-frags). D[n][m]: lanes lhi==0 hold n=r (r<4) for row l31 -> one
// float4 store per lane per frag.
__device__ __forceinline__ void layer9T(const _Float16* abuf,
                                        const half8* __restrict__ wq,
                                        const float* __restrict__ b9,
                                        float* __restrict__ out, long r0,
                                        int lane, int wave) {
    const int l31 = lane & 31, lhi = lane >> 5;
    const _Float16* aB0 = abuf + lhi * 1024 + (wave * 64 + l31) * 8;
    const _Float16* aB1 = abuf + lhi * 1024 + (wave * 64 + 32 + l31) * 8;
    floatx16 acc0 = {}, acc1 = {};
    const half8* wl = wq + lane;
    half8 wc = wl[0];
#pragma unroll 1
    for (int ks = 0; ks < 15; ks++) {
        half8 wn = wl[(ks + 1) * 64];
        half8 a0 = *(const half8*)(aB0 + ks * 2048);
        half8 a1 = *(const half8*)(aB1 + ks * 2048);
        acc0 = __builtin_amdgcn_mfma_f32_32x32x16_f16(wc, a0, acc0, 0, 0, 0);
        acc1 = __builtin_amdgcn_mfma_f32_32x32x16_f16(wc, a1, acc1, 0, 0, 0);
        wc = wn;
    }
    {
        half8 a0 = *(const half8*)(aB0 + 15 * 2048);
        half8 a1 = *(const half8*)(aB1 + 15 * 2048);
        acc0 = __builtin_amdgcn_mfma_f32_32x32x16_f16(wc, a0, acc0, 0, 0, 0);
        acc1 = __builtin_amdgcn_mfma_f32_32x32x16_f16(wc, a1, acc1, 0, 0, 0);
    }
    if (lhi == 0) {
        floatx4 b4 = *(const floatx4*)(b9);
        floatx4 o0, o1;
#pragma unroll
        for (int r = 0; r < 4; r++) {
            o0[r] = acc0[r] + b4[r];
            o1[r] = acc1[r] + b4[r];
        }
        *(floatx4*)(out + (r0 + wave * 64 + l31) * 4) = o0;
        *(floatx4*)(out + (r0 + wave * 64 + 32 + l31) * 4) = o1;
    }
}

__global__ __launch_bounds__(128, 1) void mlp_fused(
    const float* __restrict__ x, const _Float16* __restrict__ wpk,
    const float* __restrict__ b1, const float* __restrict__ b2,
    const float* __restrict__ b3, const float* __restrict__ b4,
    const float* __restrict__ b5, const float* __restrict__ b6,
    const float* __restrict__ b7, const float* __restrict__ b8,
    const float* __restrict__ b9, float* __restrict__ out) {
    // act 128x256 fp16 (64 KiB, in-place) + x 128x48 (12 KiB) = 76 KiB;
    // 2-wave blocks; 2 blocks/CU = 4 waves/CU = 1 wave/SIMD at 512-reg budget.
    __shared__ _Float16 lds[128 * 256 + 128 * 48];
    _Float16* buf = lds;
    _Float16* xbuf = lds + 128 * 256;
    const int tid = threadIdx.x;
    const int lane = tid & 63, wave = tid >> 6;
    const long r0 = (long)blockIdx.x * 128;

    // Stage x (chunk-major): zero pad cols (39..47), fill cols 0..38.
    for (int i = tid; i < 128 * 9; i += 128) {
        int row = i / 9, col = 39 + (i - row * 9);
        xbuf[cmaj(row, col)] = (_Float16)0.f;
    }
    for (int i = tid; i < 128 * 39; i += 128) {
        int row = i / 39, col = i - row * 39;
        xbuf[cmaj(row, col)] = (_Float16)x[r0 * 39 + i];  // contiguous 4992 floats
    }
    __syncthreads();

    const half8* wp = (const half8*)wpk;  // tile = 64 half8 (1 KB)
    const half8* w1q = wp + (size_t)0 * 64;
    const half8* w2q = wp + (size_t)32 * 64;
    const half8* w3q = wp + (size_t)160 * 64;
    const half8* w4q = wp + (size_t)288 * 64;
    const half8* w5q = wp + (size_t)416 * 64;
    const half8* w6q = wp + (size_t)576 * 64;
    const half8* w7q = wp + (size_t)704 * 64;
    const half8* w8q = wp + (size_t)832 * 64;
    const half8* w9q = wp + (size_t)960 * 64;

    layerT<3, 2, 0>(xbuf, xbuf, w1q, b1, buf, lane, wave);   // x -> buf (K=48)
    __syncthreads();
    layerT<16, 0, 0>(buf, xbuf, w2q, b2, buf, lane, wave);
    __syncthreads();
    layerT<16, 0, 0>(buf, xbuf, w3q, b3, buf, lane, wave);
    __syncthreads();
    layerT<16, 0, 0>(buf, xbuf, w4q, b4, buf, lane, wave);
    __syncthreads();
    layerT<19, 1, 16>(buf, xbuf, w5q, b5, buf, lane, wave);  // [h|x] skip, K=304
    __syncthreads();
    layerT<16, 0, 0>(buf, xbuf, w6q, b6, buf, lane, wave);
    __syncthreads();
    layerT<16, 0, 0>(buf, xbuf, w7q, b7, buf, lane, wave);
    __syncthreads();
    layerT<16, 0, 0>(buf, xbuf, w8q, b8, buf, lane, wave);
    __syncthreads();
    layer9T(buf, w9q, b9, out, r0, lane, wave);
}

extern "C" void kernel_launch(void* const* d_in, const int* in_sizes, int n_in,
                              void* d_out, int out_size, void* d_ws, size_t ws_size,
                              hipStream_t stream) {
    const float* x = (const float*)d_in[0];
    const float* w[9];
    const float* b[9];
    for (int i = 0; i < 9; i++) {
        w[i] = (const float*)d_in[1 + 2 * i];
        b[i] = (const float*)d_in[2 + 2 * i];
    }
    _Float16* wpk = (_Float16*)d_ws;  // 999424 B

    pack_w32<<<244, 256, 0, stream>>>(w[0], w[1], w[2], w[3], w[4], w[5], w[6], w[7], w[8], wpk);
    mlp_fused<<<262144 / 128, 128, 0, stream>>>(x, wpk, b[0], b[1], b[2], b[3], b[4],
                                                b[5], b[6], b[7], b[8], (float*)d_out);
}

// Round 2
// 328.316 us; speedup vs baseline: 1.1324x; 1.1324x over previous
//
#include <hip/hip_runtime.h>
#include <hip/hip_bf16.h>

typedef _Float16 half8 __attribute__((ext_vector_type(8)));
typedef _Float16 half4v __attribute__((ext_vector_type(4)));
typedef float floatx4 __attribute__((ext_vector_type(4)));
typedef float floatx16 __attribute__((ext_vector_type(16)));

// ---------------------------------------------------------------------------
// R18: 128x64 wave tile (4m x 2n frags, acc=128 regs), BM=128, 4-wave blocks,
// 2 blocks/CU -> 8 waves/CU = 2 waves/SIMD (from DIFFERENT blocks -> barrier
// stalls of one block covered by the other).
//
// Post-mortem R17: MFMA "8 cy" is per-CU (per-SIMD pipe = 32 cy/MFMA);
// 1 wave/SIMD caps matrix throughput at its own serial chain + exposes all
// latency (measured 28% MfmaUtil). R16 (64x64, 4/SIMD) was L2-W-bound:
// per-kstep per-CU L2 demand 585 cy > matrix 512. R18 balance per kstep/CU:
// matrix 512 cy, LDS-A 384 cy, L2-W 293 cy -> matrix-bound on paper, with
// enough wave-level parallelism (2/SIMD) to hide per-wave stalls (per-kstep
// MFMA window = 256 SIMD-cy/wave >= L2 latency with depth-1 prefetch).
//
// Act layout: chunk-major, 128-row chunks:
//   off(row, col) = (col>>3)*1024 + row*8 + (col&7)   [halfs]
// A-frag (ks, mi): base = lhi*1024 + (mi*32+l31)*8, + ks*2048 halfs
// (max act imm = 15*4096 B, fits 16-bit ds offset; L5 ks>=16 -> x buffer).
// LDS: act 128x256 fp16 (64 KiB, in-place) + x 128x48 (12 KiB) = 76 KiB.
// __launch_bounds__(256,2) -> 256-reg cap (acc 128 + ~90 arch).
// ---------------------------------------------------------------------------
__device__ __forceinline__ int cmaj(int row, int col) {
    return ((col >> 3) << 10) + (row << 3) + (col & 7);
}

// ---------------------------------------------------------------------------
// Weight pre-pack (unchanged, proven R5-R17): fp32 (K,N) row-major -> fp16
// fragment order; lane L holds W[kt*16 + 8*(L>>5) + j][nt*32 + (L&31)].
// Fed to the MFMA *A* operand so D = C^T. K zero-padded: L1 39->64 (KT=4),
// L5 295->320 (KT=20), others 256 (KT=16). L9 N 4->32. Tile starts (1KB):
// {0,32,160,288,416,576,704,832,960}, total 976 tiles = 999424 B in d_ws.
// (R18 consumes kt 0..2 of L1 and kt 0..18 of L5 — the rest is zeros.)
// ---------------------------------------------------------------------------
__global__ void pack_w32(const float* __restrict__ w1, const float* __restrict__ w2,
                         const float* __restrict__ w3, const float* __restrict__ w4,
                         const float* __restrict__ w5, const float* __restrict__ w6,
                         const float* __restrict__ w7, const float* __restrict__ w8,
                         const float* __restrict__ w9, _Float16* __restrict__ dst) {
    const int tileStart[10] = {0, 32, 160, 288, 416, 576, 704, 832, 960, 976};
    const int Ks[9] = {39, 256, 256, 256, 295, 256, 256, 256, 256};
    const int Ns[9] = {256, 256, 256, 256, 256, 256, 256, 256, 4};
    const int Tn[9] = {8, 8, 8, 8, 8, 8, 8, 8, 1};
    const float* ws[9] = {w1, w2, w3, w4, w5, w6, w7, w8, w9};

    int g = blockIdx.x * blockDim.x + threadIdx.x;
    int tile = g >> 6, lane = g & 63;
    if (tile >= 976) return;
    int layer = 0;
    while (tile >= tileStart[layer + 1]) layer++;
    int t = tile - tileStart[layer];
    int tn = Tn[layer];
    int kt = t / tn, nt = t - kt * tn;
    int k0 = kt * 16 + (lane >> 5) * 8;
    int n = nt * 32 + (lane & 31);
    const float* w = ws[layer];
    int K = Ks[layer], N = Ns[layer];
    _Float16 v[8];
#pragma unroll
    for (int j = 0; j < 8; j++) {
        int k = k0 + j;
        v[j] = (k < K && n < N) ? (_Float16)w[k * N + n] : (_Float16)0.f;
    }
    *(half8*)(dst + (size_t)tile * 512 + lane * 8) = *(half8*)v;
}

// A-fragment load: base encodes (lhi, m-frag row); offset linear in ks.
// AMODE 0: act. 1: ks>=KS0 from x (layer-5 skip). 2: entirely x (layer 1).
template <int AMODE, int KS0>
__device__ __forceinline__ half8 ldA(const _Float16* aB, const _Float16* xB, int ks) {
    if (AMODE == 2) return *(const half8*)(xB + ks * 2048);
    if (AMODE == 1 && ks >= KS0) return *(const half8*)(xB + (ks - KS0) * 2048);
    return *(const half8*)(aB + ks * 2048);
}

// ---------------------------------------------------------------------------
// One fused layer: C(128x256) = relu(A(128xK) @ W + b), in-place LDS->LDS.
// Wave tile 128x64: per kstep 4 A-frags (ds_read_b128, reused across both
// n-frags) + 2 W-frags (global 16B, L2-resident) + 8 MFMA; depth-1 prefetch
// of both streams. Bias folded into acc init; b64 epilogue.
// ---------------------------------------------------------------------------
template <int KT, int AMODE, int KS0>
__device__ __forceinline__ void layerT(const _Float16* abuf,
                                       const _Float16* __restrict__ xbuf,
                                       const half8* __restrict__ wq,
                                       const float* __restrict__ bias,
                                       _Float16* obuf,
                                       int lane, int wave) {
    const int l31 = lane & 31, lhi = lane >> 5;
    const _Float16* aB[4];
    const _Float16* xB[4];
#pragma unroll
    for (int mi = 0; mi < 4; mi++) {
        aB[mi] = abuf + lhi * 1024 + (mi * 32 + l31) * 8;
        xB[mi] = xbuf + lhi * 1024 + (mi * 32 + l31) * 8;
    }
    // W frag (kstep ks, n-tile wave*2+ni): wl[ks*512 + ni*64]
    const half8* wl = wq + (wave * 2) * 64 + lane;

    // Bias -> acc init: acc element g*4+r is channel wave*64 + ni*32 + lhi*4 + g*8 + r.
    floatx16 acc[4][2];
#pragma unroll
    for (int ni = 0; ni < 2; ni++) {
        floatx16 t;
#pragma unroll
        for (int g = 0; g < 4; g++) {
            floatx4 b = *(const floatx4*)(bias + wave * 64 + ni * 32 + g * 8 + lhi * 4);
#pragma unroll
            for (int r = 0; r < 4; r++) t[g * 4 + r] = b[r];
        }
#pragma unroll
        for (int mi = 0; mi < 4; mi++) acc[mi][ni] = t;
    }

    half8 wc[2], ac[4];
#pragma unroll
    for (int ni = 0; ni < 2; ni++) wc[ni] = wl[ni * 64];
#pragma unroll
    for (int mi = 0; mi < 4; mi++) ac[mi] = ldA<AMODE, KS0>(aB[mi], xB[mi], 0);

#pragma unroll 1
    for (int ks = 0; ks < KT - 1; ks++) {
        half8 wn[2], an[4];
#pragma unroll
        for (int ni = 0; ni < 2; ni++) wn[ni] = wl[(ks + 1) * 512 + ni * 64];
#pragma unroll
        for (int mi = 0; mi < 4; mi++) an[mi] = ldA<AMODE, KS0>(aB[mi], xB[mi], ks + 1);
#pragma unroll
        for (int mi = 0; mi < 4; mi++)
#pragma unroll
            for (int ni = 0; ni < 2; ni++)
                acc[mi][ni] = __builtin_amdgcn_mfma_f32_32x32x16_f16(wc[ni], ac[mi],
                                                                     acc[mi][ni], 0, 0, 0);
#pragma unroll
        for (int ni = 0; ni < 2; ni++) wc[ni] = wn[ni];
#pragma unroll
        for (int mi = 0; mi < 4; mi++) ac[mi] = an[mi];
    }
#pragma unroll
    for (int mi = 0; mi < 4; mi++)
#pragma unroll
        for (int ni = 0; ni < 2; ni++)
            acc[mi][ni] = __builtin_amdgcn_mfma_f32_32x32x16_f16(wc[ni], ac[mi],
                                                                 acc[mi][ni], 0, 0, 0);

    // In-place safety barrier: all waves' act-reads complete before any write.
    if (AMODE != 2) __syncthreads();
    // Epilogue: relu + fp16 cvt + b64 writes (bias already in acc).
    // col = wave*64 + ni*32 + g*8 + lhi*4 + r -> chunk = wave*8 + ni*4 + g,
    // inner = lhi*4 + r; row = mi*32 + l31.
#pragma unroll
    for (int mi = 0; mi < 4; mi++) {
        _Float16* ob = obuf + (mi * 32 + l31) * 8 + lhi * 4;
#pragma unroll
        for (int ni = 0; ni < 2; ni++) {
#pragma unroll
            for (int g = 0; g < 4; g++) {
                half4v h;
#pragma unroll
                for (int r = 0; r < 4; r++) {
                    float v = acc[mi][ni][g * 4 + r];
                    v = v > 0.f ? v : 0.f;
                    h[r] = (_Float16)v;
                }
                *(half4v*)(ob + (wave * 8 + ni * 4 + g) * 1024) = h;
            }
        }
    }
}

// Layer 9 (swapped): 256 -> 4 (N padded to 32). Each of 4 waves takes one
// 32-row m-frag. D[n][m]: lanes lhi==0 hold n=r (r<4) for row l31 -> one
// float4 store per lane.
__device__ __forceinline__ void layer9T(const _Float16* abuf,
                                        const half8* __restrict__ wq,
                                        const float* __restrict__ b9,
                                        float* __restrict__ out, long r0,
                                        int lane, int wave) {
    const int l31 = lane & 31, lhi = lane >> 5;
    const _Float16* aB = abuf + lhi * 1024 + (wave * 32 + l31) * 8;
    floatx16 acc = {};
    const half8* wl = wq + lane;
    half8 wc = wl[0];
#pragma unroll 1
    for (int ks = 0; ks < 15; ks++) {
        half8 wn = wl[(ks + 1) * 64];
        half8 a = *(const half8*)(aB + ks * 2048);
        acc = __builtin_amdgcn_mfma_f32_32x32x16_f16(wc, a, acc, 0, 0, 0);
        wc = wn;
    }
    {
        half8 a = *(const half8*)(aB + 15 * 2048);
        acc = __builtin_amdgcn_mfma_f32_32x32x16_f16(wc, a, acc, 0, 0, 0);
    }
    if (lhi == 0) {
        floatx4 b4 = *(const floatx4*)(b9);
        floatx4 o;
#pragma unroll
        for (int r = 0; r < 4; r++) o[r] = acc[r] + b4[r];
        *(floatx4*)(out + (r0 + wave * 32 + l31) * 4) = o;
    }
}

__global__ __launch_bounds__(256, 2) void mlp_fused(
    const float* __restrict__ x, const _Float16* __restrict__ wpk,
    const float* __restrict__ b1, const float* __restrict__ b2,
    const float* __restrict__ b3, const float* __restrict__ b4,
    const float* __restrict__ b5, const float* __restrict__ b6,
    const float* __restrict__ b7, const float* __restrict__ b8,
    const float* __restrict__ b9, float* __restrict__ out) {
    // act 128x256 fp16 (64 KiB, in-place) + x 128x48 (12 KiB) = 76 KiB;
    // 4-wave blocks; 2 blocks/CU = 8 waves/CU = 2 waves/SIMD (256-reg cap).
    __shared__ _Float16 lds[128 * 256 + 128 * 48];
    _Float16* buf = lds;
    _Float16* xbuf = lds + 128 * 256;
    const int tid = threadIdx.x;
    const int lane = tid & 63, wave = tid >> 6;
    const long r0 = (long)blockIdx.x * 128;

    // Stage x (chunk-major): zero pad cols (39..47), fill cols 0..38.
    for (int i = tid; i < 128 * 9; i += 256) {
        int row = i / 9, col = 39 + (i - row * 9);
        xbuf[cmaj(row, col)] = (_Float16)0.f;
    }
    for (int i = tid; i < 128 * 39; i += 256) {
        int row = i / 39, col = i - row * 39;
        xbuf[cmaj(row, col)] = (_Float16)x[r0 * 39 + i];  // contiguous 4992 floats
    }
    __syncthreads();

    const half8* wp = (const half8*)wpk;  // tile = 64 half8 (1 KB)
    const half8* w1q = wp + (size_t)0 * 64;
    const half8* w2q = wp + (size_t)32 * 64;
    const half8* w3q = wp + (size_t)160 * 64;
    const half8* w4q = wp + (size_t)288 * 64;
    const half8* w5q = wp + (size_t)416 * 64;
    const half8* w6q = wp + (size_t)576 * 64;
    const half8* w7q = wp + (size_t)704 * 64;
    const half8* w8q = wp + (size_t)832 * 64;
    const half8* w9q = wp + (size_t)960 * 64;

    layerT<3, 2, 0>(xbuf, xbuf, w1q, b1, buf, lane, wave);   // x -> buf (K=48)
    __syncthreads();
    layerT<16, 0, 0>(buf, xbuf, w2q, b2, buf, lane, wave);
    __syncthreads();
    layerT<16, 0, 0>(buf, xbuf, w3q, b3, buf, lane, wave);
    __syncthreads();
    layerT<16, 0, 0>(buf, xbuf, w4q, b4, buf, lane, wave);
    __syncthreads();
    layerT<19, 1, 16>(buf, xbuf, w5q, b5, buf, lane, wave);  // [h|x] skip, K=304
    __syncthreads();
    layerT<16, 0, 0>(buf, xbuf, w6q, b6, buf, lane, wave);
    __syncthreads();
    layerT<16, 0, 0>(buf, xbuf, w7q, b7, buf, lane, wave);
    __syncthreads();
    layerT<16, 0, 0>(buf, xbuf, w8q, b8, buf, lane, wave);
    __syncthreads();
    layer9T(buf, w9q, b9, out, r0, lane, wave);
}

extern "C" void kernel_launch(void* const* d_in, const int* in_sizes, int n_in,
                              void* d_out, int out_size, void* d_ws, size_t ws_size,
                              hipStream_t stream) {
    const float* x = (const float*)d_in[0];
    const float* w[9];
    const float* b[9];
    for (int i = 0; i < 9; i++) {
        w[i] = (const float*)d_in[1 + 2 * i];
        b[i] = (const float*)d_in[2 + 2 * i];
    }
    _Float16* wpk = (_Float16*)d_ws;  // 999424 B

    pack_w32<<<244, 256, 0, stream>>>(w[0], w[1], w[2], w[3], w[4], w[5], w[6], w[7], w[8], wpk);
    mlp_fused<<<262144 / 128, 256, 0, stream>>>(x, wpk, b[0], b[1], b[2], b[3], b[4],
                                                b[5], b[6], b[7], b[8], (float*)d_out);
}